// Round 1
// baseline (3494.163 us; speedup 1.0000x reference)
//
#include <hip/hip_runtime.h>
#include <math.h>

// Problem constants
#define BATCH 2
#define SEQ   2048
#define DMODEL 1024
#define NHEAD 16
#define DK    64
#define EPS   1e-6f

// ---------------- generic tiled fp32 GEMM: Y[M,N] = X[M,K] @ W[K,N] ----------------
#define BM 64
#define BN 64
#define BKC 16

__global__ __launch_bounds__(256) void gemm_xw(const float* __restrict__ X,
                                               const float* __restrict__ W,
                                               float* __restrict__ Y,
                                               int M, int N, int K) {
    __shared__ float As[BKC][BM];
    __shared__ float Bs[BKC][BN];
    const int bm = blockIdx.y * BM;
    const int bn = blockIdx.x * BN;
    const int tid = threadIdx.x;
    const int tx = tid & 15;       // 0..15 -> N
    const int ty = tid >> 4;       // 0..15 -> M
    float acc[4][4] = {};
    for (int k0 = 0; k0 < K; k0 += BKC) {
        // load A tile 64x16 (1024 elems, 4/thread), coalesced over k
        #pragma unroll
        for (int i = tid; i < BM * BKC; i += 256) {
            int m = i >> 4, kk = i & 15;
            As[kk][m] = X[(size_t)(bm + m) * K + (k0 + kk)];
        }
        // load B tile 16x64, coalesced over n
        #pragma unroll
        for (int i = tid; i < BKC * BN; i += 256) {
            int kk = i >> 6, n = i & 63;
            Bs[kk][n] = W[(size_t)(k0 + kk) * N + (bn + n)];
        }
        __syncthreads();
        #pragma unroll
        for (int kk = 0; kk < BKC; ++kk) {
            float a[4], b[4];
            #pragma unroll
            for (int i = 0; i < 4; ++i) a[i] = As[kk][ty * 4 + i];
            #pragma unroll
            for (int j = 0; j < 4; ++j) b[j] = Bs[kk][tx * 4 + j];
            #pragma unroll
            for (int i = 0; i < 4; ++i)
                #pragma unroll
                for (int j = 0; j < 4; ++j)
                    acc[i][j] += a[i] * b[j];
        }
        __syncthreads();
    }
    #pragma unroll
    for (int i = 0; i < 4; ++i)
        #pragma unroll
        for (int j = 0; j < 4; ++j)
            Y[(size_t)(bm + ty * 4 + i) * N + (bn + tx * 4 + j)] = acc[i][j];
}

// ---------------- scores: S[bh, q, k] = (Q . K)/8, masked -> -1e9 ----------------
// grid: (L/64 kt, L/64 qt, B*H), block 256
__global__ __launch_bounds__(256) void scores_kernel(const float* __restrict__ Qp,
                                                     const float* __restrict__ Kp,
                                                     const int* __restrict__ mask,
                                                     float* __restrict__ S) {
    const int bh = blockIdx.z;
    const int b = bh >> 4, h = bh & 15;
    const int qt = blockIdx.y * 64;
    const int kt = blockIdx.x * 64;
    __shared__ float Qs[DK][64 + 1];
    __shared__ float Ks[DK][64 + 1];
    const int tid = threadIdx.x;
    const int tx = tid & 15, ty = tid >> 4;
    // load 64 rows x 64 dims each; global reads coalesced over dk
    #pragma unroll
    for (int i = tid; i < 64 * DK; i += 256) {
        int m = i >> 6, kd = i & 63;
        Qs[kd][m] = Qp[((size_t)b * SEQ + (qt + m)) * DMODEL + h * DK + kd];
        Ks[kd][m] = Kp[((size_t)b * SEQ + (kt + m)) * DMODEL + h * DK + kd];
    }
    __syncthreads();
    float acc[4][4] = {};
    #pragma unroll
    for (int kd = 0; kd < DK; ++kd) {
        float a[4], bb[4];
        #pragma unroll
        for (int i = 0; i < 4; ++i) a[i] = Qs[kd][ty * 4 + i];
        #pragma unroll
        for (int j = 0; j < 4; ++j) bb[j] = Ks[kd][tx * 4 + j];
        #pragma unroll
        for (int i = 0; i < 4; ++i)
            #pragma unroll
            for (int j = 0; j < 4; ++j)
                acc[i][j] += a[i] * bb[j];
    }
    #pragma unroll
    for (int i = 0; i < 4; ++i) {
        int lq = qt + ty * 4 + i;
        #pragma unroll
        for (int j = 0; j < 4; ++j) {
            int lk = kt + tx * 4 + j;
            int mval = mask[((size_t)b * SEQ + lq) * SEQ + lk];
            float v = mval ? -1e9f : acc[i][j] * 0.125f;
            S[((size_t)bh * SEQ + lq) * SEQ + lk] = v;
        }
    }
}

// ---------------- softmax in place over last dim (row length 2048) ----------------
__global__ __launch_bounds__(256) void softmax_kernel(float* __restrict__ S) {
    __shared__ float sm[256];
    const int tid = threadIdx.x;
    float* row = S + (size_t)blockIdx.x * SEQ;
    float vals[8];
    float m = -1e30f;
    #pragma unroll
    for (int i = 0; i < 8; ++i) {
        vals[i] = row[tid + i * 256];
        m = fmaxf(m, vals[i]);
    }
    sm[tid] = m; __syncthreads();
    for (int s = 128; s > 0; s >>= 1) {
        if (tid < s) sm[tid] = fmaxf(sm[tid], sm[tid + s]);
        __syncthreads();
    }
    m = sm[0]; __syncthreads();
    float ssum = 0.f;
    #pragma unroll
    for (int i = 0; i < 8; ++i) {
        vals[i] = __expf(vals[i] - m);
        ssum += vals[i];
    }
    sm[tid] = ssum; __syncthreads();
    for (int s = 128; s > 0; s >>= 1) {
        if (tid < s) sm[tid] += sm[tid + s];
        __syncthreads();
    }
    float inv = 1.0f / sm[0];
    #pragma unroll
    for (int i = 0; i < 8; ++i)
        row[tid + i * 256] = vals[i] * inv;
}

// ---------------- PV: O[b, q, h*64+dk] = sum_k attn[bh,q,k] * V[b,k,h*64+dk] ----------------
// grid: (L/64 qt, B*H), block 256
__global__ __launch_bounds__(256) void pv_kernel(const float* __restrict__ Attn,
                                                 const float* __restrict__ V,
                                                 float* __restrict__ O) {
    const int bh = blockIdx.y;
    const int b = bh >> 4, h = bh & 15;
    const int qt = blockIdx.x * 64;
    const float* A = Attn + (size_t)bh * SEQ * SEQ;
    __shared__ float As[BKC][BM];
    __shared__ float Bs[BKC][BN + 1];
    const int tid = threadIdx.x;
    const int tx = tid & 15, ty = tid >> 4;
    float acc[4][4] = {};
    for (int k0 = 0; k0 < SEQ; k0 += BKC) {
        #pragma unroll
        for (int i = tid; i < BM * BKC; i += 256) {
            int m = i >> 4, kk = i & 15;
            As[kk][m] = A[(size_t)(qt + m) * SEQ + (k0 + kk)];
        }
        #pragma unroll
        for (int i = tid; i < BKC * BN; i += 256) {
            int kk = i >> 6, n = i & 63;
            Bs[kk][n] = V[((size_t)b * SEQ + (k0 + kk)) * DMODEL + h * DK + n];
        }
        __syncthreads();
        #pragma unroll
        for (int kk = 0; kk < BKC; ++kk) {
            float a[4], bb[4];
            #pragma unroll
            for (int i = 0; i < 4; ++i) a[i] = As[kk][ty * 4 + i];
            #pragma unroll
            for (int j = 0; j < 4; ++j) bb[j] = Bs[kk][tx * 4 + j];
            #pragma unroll
            for (int i = 0; i < 4; ++i)
                #pragma unroll
                for (int j = 0; j < 4; ++j)
                    acc[i][j] += a[i] * bb[j];
        }
        __syncthreads();
    }
    #pragma unroll
    for (int i = 0; i < 4; ++i)
        #pragma unroll
        for (int j = 0; j < 4; ++j)
            O[((size_t)b * SEQ + (qt + ty * 4 + i)) * DMODEL + h * DK + tx * 4 + j] = acc[i][j];
}

// ---------------- residual + layernorm ----------------
// one block per (b,l) row of 1024; block 256
__global__ __launch_bounds__(256) void ln_kernel(const float* __restrict__ O,
                                                 const float* __restrict__ Qin,
                                                 const float* __restrict__ g,
                                                 const float* __restrict__ bt,
                                                 float* __restrict__ out) {
    __shared__ float sm[256];
    const int tid = threadIdx.x;
    const size_t base = (size_t)blockIdx.x * DMODEL;
    float v[4];
    float s = 0.f, s2 = 0.f;
    #pragma unroll
    for (int i = 0; i < 4; ++i) {
        int d = tid + i * 256;
        float x = O[base + d] + Qin[base + d];
        v[i] = x;
        s += x;
        s2 += x * x;
    }
    sm[tid] = s; __syncthreads();
    for (int st = 128; st > 0; st >>= 1) {
        if (tid < st) sm[tid] += sm[tid + st];
        __syncthreads();
    }
    s = sm[0]; __syncthreads();
    sm[tid] = s2; __syncthreads();
    for (int st = 128; st > 0; st >>= 1) {
        if (tid < st) sm[tid] += sm[tid + st];
        __syncthreads();
    }
    s2 = sm[0];
    const float mu = s * (1.0f / DMODEL);
    const float var = s2 * (1.0f / DMODEL) - mu * mu;
    const float r = rsqrtf(var + EPS);
    #pragma unroll
    for (int i = 0; i < 4; ++i) {
        int d = tid + i * 256;
        out[base + d] = (v[i] - mu) * r * g[d] + bt[d];
    }
}

extern "C" void kernel_launch(void* const* d_in, const int* in_sizes, int n_in,
                              void* d_out, int out_size, void* d_ws, size_t ws_size,
                              hipStream_t stream) {
    const float* key   = (const float*)d_in[0];
    const float* value = (const float*)d_in[1];
    const float* query = (const float*)d_in[2];
    const int*   mask  = (const int*)  d_in[3];
    const float* W_k   = (const float*)d_in[4];
    const float* W_v   = (const float*)d_in[5];
    const float* W_q   = (const float*)d_in[6];
    const float* ln_g  = (const float*)d_in[7];
    const float* ln_b  = (const float*)d_in[8];

    float* out      = (float*)d_out;                       // normed: B*L*D
    float* attn_out = out + (size_t)BATCH * SEQ * DMODEL;  // attn: B*H*L*L

    const size_t NPROJ = (size_t)BATCH * SEQ * DMODEL;     // 4,194,304
    float* q_up = (float*)d_ws;
    float* k_up = q_up + NPROJ;
    float* v_up = k_up + NPROJ;
    float* o_ws = v_up + NPROJ;

    const int M = BATCH * SEQ;   // 4096
    dim3 gproj(DMODEL / BN, M / BM);   // (16, 64)
    gemm_xw<<<gproj, 256, 0, stream>>>(key,   W_k, k_up, M, DMODEL, DMODEL);
    gemm_xw<<<gproj, 256, 0, stream>>>(value, W_v, v_up, M, DMODEL, DMODEL);
    gemm_xw<<<gproj, 256, 0, stream>>>(query, W_q, q_up, M, DMODEL, DMODEL);

    dim3 gsc(SEQ / 64, SEQ / 64, BATCH * NHEAD);  // (32, 32, 32)
    scores_kernel<<<gsc, 256, 0, stream>>>(q_up, k_up, mask, attn_out);

    softmax_kernel<<<BATCH * NHEAD * SEQ, 256, 0, stream>>>(attn_out);

    dim3 gpv(SEQ / 64, BATCH * NHEAD);  // (32, 32)
    pv_kernel<<<gpv, 256, 0, stream>>>(attn_out, v_up, o_ws);

    ln_kernel<<<BATCH * SEQ, 256, 0, stream>>>(o_ws, query, ln_g, ln_b, out);
}

// Round 2
// 1055.907 us; speedup vs baseline: 3.3092x; 3.3092x over previous
//
#include <hip/hip_runtime.h>
#include <math.h>

// Problem constants
#define BATCH 2
#define SEQ   2048
#define DMODEL 1024
#define NHEAD 16
#define DK    64
#define EPS   1e-6f

typedef unsigned short ushort_t;
typedef __attribute__((ext_vector_type(8))) __bf16 bf16x8;
typedef __attribute__((ext_vector_type(4))) float f32x4;
typedef __attribute__((ext_vector_type(4))) unsigned int uivec4;

union B8U { uivec4 u; bf16x8 v; };

__device__ __forceinline__ ushort_t f2b(float x) {
    union { float f; unsigned int u; } c; c.f = x;
    unsigned int r = (c.u + 0x7fffu + ((c.u >> 16) & 1u)) >> 16;
    return (ushort_t)r;
}
__device__ __forceinline__ float b2f(ushort_t b) {
    union { unsigned int u; float f; } c; c.u = ((unsigned int)b) << 16;
    return c.f;
}
__device__ __forceinline__ bf16x8 ld_frag_lds(const ushort_t* p) {
    B8U t; t.u = *reinterpret_cast<const uivec4*>(p); return t.v;
}
__device__ __forceinline__ bf16x8 ld_frag_glb(const ushort_t* p) {
    B8U t; t.u = *reinterpret_cast<const uivec4*>(p); return t.v;
}
#define MFMA16(a, b, c) __builtin_amdgcn_mfma_f32_16x16x32_bf16((a), (b), (c), 0, 0, 0)

// =============== bf16 MFMA projection GEMM: Y[4096,1024](bf16) = X(fp32) @ W(fp32) ===============
// 128x128 tile, 256 threads (4 waves), each wave 64x64 (4x4 MFMA tiles), BK=32.
#define AST 40   // LDS row stride (ushorts) for A tile (32 + 8 pad)
#define BST 40
__global__ __launch_bounds__(256) void gemm_proj(const float* __restrict__ X,
                                                 const float* __restrict__ W,
                                                 ushort_t* __restrict__ Y) {
    __shared__ __align__(16) ushort_t As[128 * AST];
    __shared__ __align__(16) ushort_t Bt[128 * BST];
    const int t = threadIdx.x;
    const int bm = blockIdx.y * 128;
    const int bn = blockIdx.x * 128;
    const int w = t >> 6, lane = t & 63;
    const int ln16 = lane & 15, quad = lane >> 4;
    const int wr = w >> 1, wc = w & 1;

    f32x4 acc[4][4] = {};

    for (int k0 = 0; k0 < DMODEL; k0 += 32) {
        // stage A: 128 rows x 32 k, fp32 -> bf16
        {
            const int m = t >> 1, half = t & 1;
            const float* src = X + (size_t)(bm + m) * DMODEL + k0 + half * 16;
            ushort_t* dst = &As[m * AST + half * 16];
            #pragma unroll
            for (int i = 0; i < 16; ++i) dst[i] = f2b(src[i]);
        }
        // stage B transposed: Bt[n][kk] = W[k0+kk][bn+n]
        {
            const int kk = t >> 3, n0 = (t & 7) * 16;
            const float* src = W + (size_t)(k0 + kk) * DMODEL + bn + n0;
            #pragma unroll
            for (int i = 0; i < 16; ++i) Bt[(n0 + i) * BST + kk] = f2b(src[i]);
        }
        __syncthreads();
        bf16x8 af[4], bfr[4];
        #pragma unroll
        for (int rt = 0; rt < 4; ++rt)
            af[rt] = ld_frag_lds(&As[(wr * 64 + rt * 16 + ln16) * AST + quad * 8]);
        #pragma unroll
        for (int ct = 0; ct < 4; ++ct)
            bfr[ct] = ld_frag_lds(&Bt[(wc * 64 + ct * 16 + ln16) * BST + quad * 8]);
        #pragma unroll
        for (int rt = 0; rt < 4; ++rt)
            #pragma unroll
            for (int ct = 0; ct < 4; ++ct)
                acc[rt][ct] = MFMA16(af[rt], bfr[ct], acc[rt][ct]);
        __syncthreads();
    }
    // epilogue: C row = quad*4 + reg, col = ln16
    #pragma unroll
    for (int rt = 0; rt < 4; ++rt) {
        #pragma unroll
        for (int ct = 0; ct < 4; ++ct) {
            #pragma unroll
            for (int r = 0; r < 4; ++r) {
                int row = bm + wr * 64 + rt * 16 + quad * 4 + r;
                int col = bn + wc * 64 + ct * 16 + ln16;
                Y[(size_t)row * DMODEL + col] = f2b(acc[rt][ct][r]);
            }
        }
    }
}

// =============== transpose V: v_up[b][seq][h*64+dk] -> v_t[(b*16+h)*64+dk][seq] ===============
__global__ __launch_bounds__(256) void transpose_v(const ushort_t* __restrict__ v_up,
                                                   ushort_t* __restrict__ v_t) {
    __shared__ ushort_t tile[64][68];
    const int t = threadIdx.x;
    const int s0 = blockIdx.x * 64;
    const int bh = blockIdx.y;
    const int b = bh >> 4, h = bh & 15;
    {
        const int r = t >> 2, c0 = (t & 3) * 16;
        const ushort_t* src = v_up + ((size_t)b * SEQ + s0 + r) * DMODEL + h * DK + c0;
        #pragma unroll
        for (int i = 0; i < 16; ++i) tile[r][c0 + i] = src[i];
    }
    __syncthreads();
    {
        const int c = t >> 2, r0 = (t & 3) * 16;
        ushort_t* dst = v_t + ((size_t)bh * DK + c) * SEQ + s0 + r0;
        #pragma unroll
        for (int i = 0; i < 16; ++i) dst[i] = tile[r0 + i][c];
    }
}

// =============== fused attention: scores -> softmax -> attn write -> PV ===============
// block: (bh, q-tile of 32 rows), 512 threads (8 waves). Scores strip (bf16) in LDS.
#define SROW 2056   // 2048 + 8 pad (ushorts); row stride 4112 B (16B-aligned)
__global__ __launch_bounds__(512) void attn_fused(const ushort_t* __restrict__ q_up,
                                                  const ushort_t* __restrict__ k_up,
                                                  const ushort_t* __restrict__ v_t,
                                                  const int* __restrict__ mask,
                                                  float* __restrict__ attn,
                                                  float* __restrict__ o_ws) {
    __shared__ __align__(16) ushort_t sS[32 * SROW];   // 131,584 B
    __shared__ float psum[32][16];
    __shared__ float inv_s[32];

    const int t = threadIdx.x;
    const int w = t >> 6, lane = t & 63;
    const int ln16 = lane & 15, quad = lane >> 4;
    const int q0 = blockIdx.x * 32;
    const int bh = blockIdx.y;
    const int b = bh >> 4, h = bh & 15;

    // --- load Q fragments (32 rows x 64 dk) into registers: A[m][k], m=ln16, k=quad*8+j
    bf16x8 aq[2][2];
    #pragma unroll
    for (int rt = 0; rt < 2; ++rt)
        #pragma unroll
        for (int ks = 0; ks < 2; ++ks)
            aq[rt][ks] = ld_frag_glb(
                &q_up[((size_t)b * SEQ + q0 + rt * 16 + ln16) * DMODEL + h * DK + ks * 32 + quad * 8]);

    // --- phase 1: scores + exp -> LDS (no syncs needed; waves independent)
    for (int i = 0; i < 16; ++i) {
        const int ct = i * 8 + w;
        const int kt = ct * 16;
        const int col = kt + ln16;
        bf16x8 bk[2];
        #pragma unroll
        for (int ks = 0; ks < 2; ++ks)
            bk[ks] = ld_frag_glb(
                &k_up[((size_t)b * SEQ + kt + ln16) * DMODEL + h * DK + ks * 32 + quad * 8]);
        #pragma unroll
        for (int rt = 0; rt < 2; ++rt) {
            f32x4 c = {0.f, 0.f, 0.f, 0.f};
            c = MFMA16(aq[rt][0], bk[0], c);
            c = MFMA16(aq[rt][1], bk[1], c);
            #pragma unroll
            for (int r = 0; r < 4; ++r) {
                const int row = rt * 16 + quad * 4 + r;
                const int mv = mask[((size_t)b * SEQ + q0 + row) * SEQ + col];
                const float p = mv ? 0.f : __expf(c[r] * 0.125f);
                sS[row * SROW + col] = f2b(p);
            }
        }
    }
    __syncthreads();

    // --- phase 2: row sums
    {
        const int row = t >> 4, l16 = t & 15;
        float s = 0.f;
        for (int st = 0; st < 32; ++st) {
            const int col = l16 * 4 + st * 64;
            const ushort_t* p = &sS[row * SROW + col];
            s += b2f(p[0]) + b2f(p[1]) + b2f(p[2]) + b2f(p[3]);
        }
        psum[row][l16] = s;
    }
    __syncthreads();
    if (t < 32) {
        float s = 0.f;
        #pragma unroll
        for (int j = 0; j < 16; ++j) s += psum[t][j];
        inv_s[t] = 1.f / s;
    }
    __syncthreads();

    // --- phase 3: normalize in LDS + write attn (fp32) to global
    {
        const int row = t >> 4, l16 = t & 15;
        const float inv = inv_s[row];
        float* arow = attn + ((size_t)bh * SEQ + q0 + row) * SEQ;
        for (int st = 0; st < 32; ++st) {
            const int col = l16 * 4 + st * 64;
            ushort_t* p = &sS[row * SROW + col];
            float4 o;
            float v0 = b2f(p[0]) * inv;
            float v1 = b2f(p[1]) * inv;
            float v2 = b2f(p[2]) * inv;
            float v3 = b2f(p[3]) * inv;
            p[0] = f2b(v0); p[1] = f2b(v1); p[2] = f2b(v2); p[3] = f2b(v3);
            o.x = v0; o.y = v1; o.z = v2; o.w = v3;
            *reinterpret_cast<float4*>(arow + col) = o;
        }
    }
    __syncthreads();

    // --- phase 4: PV. wave w -> out tile (rt = w>>2 rows, ct = w&3 dk-cols)
    {
        const int rt = w >> 2, ct = w & 3;
        f32x4 acc = {0.f, 0.f, 0.f, 0.f};
        const ushort_t* arow = &sS[(rt * 16 + ln16) * SROW + quad * 8];
        const ushort_t* vrow = &v_t[((size_t)bh * DK + ct * 16 + ln16) * SEQ + quad * 8];
        #pragma unroll 8
        for (int k0 = 0; k0 < SEQ; k0 += 32) {
            bf16x8 a = ld_frag_lds(arow + k0);
            bf16x8 vb = ld_frag_glb(vrow + k0);
            acc = MFMA16(a, vb, acc);
        }
        #pragma unroll
        for (int r = 0; r < 4; ++r) {
            const int row = q0 + rt * 16 + quad * 4 + r;
            const int col = h * DK + ct * 16 + ln16;
            o_ws[((size_t)b * SEQ + row) * DMODEL + col] = acc[r];
        }
    }
}

// =============== residual + layernorm ===============
__global__ __launch_bounds__(256) void ln_kernel(const float* __restrict__ O,
                                                 const float* __restrict__ Qin,
                                                 const float* __restrict__ g,
                                                 const float* __restrict__ bt,
                                                 float* __restrict__ out) {
    __shared__ float sm[256];
    const int tid = threadIdx.x;
    const size_t base = (size_t)blockIdx.x * DMODEL;
    float v[4];
    float s = 0.f, s2 = 0.f;
    #pragma unroll
    for (int i = 0; i < 4; ++i) {
        int d = tid + i * 256;
        float x = O[base + d] + Qin[base + d];
        v[i] = x;
        s += x;
        s2 += x * x;
    }
    sm[tid] = s; __syncthreads();
    for (int st = 128; st > 0; st >>= 1) {
        if (tid < st) sm[tid] += sm[tid + st];
        __syncthreads();
    }
    s = sm[0]; __syncthreads();
    sm[tid] = s2; __syncthreads();
    for (int st = 128; st > 0; st >>= 1) {
        if (tid < st) sm[tid] += sm[tid + st];
        __syncthreads();
    }
    s2 = sm[0];
    const float mu = s * (1.0f / DMODEL);
    const float var = s2 * (1.0f / DMODEL) - mu * mu;
    const float r = rsqrtf(var + EPS);
    #pragma unroll
    for (int i = 0; i < 4; ++i) {
        int d = tid + i * 256;
        out[base + d] = (v[i] - mu) * r * g[d] + bt[d];
    }
}

extern "C" void kernel_launch(void* const* d_in, const int* in_sizes, int n_in,
                              void* d_out, int out_size, void* d_ws, size_t ws_size,
                              hipStream_t stream) {
    const float* key   = (const float*)d_in[0];
    const float* value = (const float*)d_in[1];
    const float* query = (const float*)d_in[2];
    const int*   mask  = (const int*)  d_in[3];
    const float* W_k   = (const float*)d_in[4];
    const float* W_v   = (const float*)d_in[5];
    const float* W_q   = (const float*)d_in[6];
    const float* ln_g  = (const float*)d_in[7];
    const float* ln_b  = (const float*)d_in[8];

    float* out      = (float*)d_out;                       // normed: B*L*D
    float* attn_out = out + (size_t)BATCH * SEQ * DMODEL;  // attn: B*H*L*L

    const size_t NPROJ = (size_t)BATCH * SEQ * DMODEL;     // 4,194,304
    ushort_t* k_up = (ushort_t*)d_ws;
    ushort_t* v_up = k_up + NPROJ;
    ushort_t* q_up = v_up + NPROJ;
    ushort_t* v_t  = q_up + NPROJ;
    float*    o_ws = (float*)(v_t + NPROJ);

    dim3 gproj(DMODEL / 128, (BATCH * SEQ) / 128);   // (8, 32)
    gemm_proj<<<gproj, 256, 0, stream>>>(key,   W_k, k_up);
    gemm_proj<<<gproj, 256, 0, stream>>>(value, W_v, v_up);
    gemm_proj<<<gproj, 256, 0, stream>>>(query, W_q, q_up);

    dim3 gtr(SEQ / 64, BATCH * NHEAD);               // (32, 32)
    transpose_v<<<gtr, 256, 0, stream>>>(v_up, v_t);

    dim3 gat(SEQ / 32, BATCH * NHEAD);               // (64, 32)
    attn_fused<<<gat, 512, 0, stream>>>(q_up, k_up, v_t, mask, attn_out, o_ws);

    ln_kernel<<<BATCH * SEQ, 256, 0, stream>>>(o_ws, query, ln_g, ln_b, out);
}